// Round 3
// baseline (81.909 us; speedup 1.0000x reference)
//
#include <hip/hip_runtime.h>
#include <hip/hip_fp16.h>
#include <math.h>

// Problem constants (match reference)
#define B_ROWS 4096
#define D_DIM  512
#define N_ROWS 8192
#define R_NEG  4

// 1/(TEMPERATURE + EPSILON): fp32(1/(0.5+1e-8)) == 2.0f (verified absmax 0.0 in R1)
#define INV_T 2.0f

#define NORM_BLOCKS (N_ROWS / 4)  // kernel A: 4 waves/block, 1 row/wave
#define LOSS_BLOCKS (N_ROWS / 4)  // kernel B: 4 waves/block, 1 row/wave
#define RED_ITERS   (LOSS_BLOCKS / 256)

// Journal:
//  R0-R4 (prev session): fill = 268MB workspace poison @6.4TB/s = ~42us fixed
//    floor in the timed window. No atomics (R3: ~30cyc/atomic serialization),
//    no device fence (R2: +81us, 38MB overfetch).
//  R5: 2x occupancy on loss kernel -> NULL. Not latency/occupancy-bound.
//  R6: fp16 normalized copy (halved gather bytes) -> kernels 37.6 -> ~31us
//    only (predicted ~16). Weakly byte-bound. Fill drifted 41->46.5us.
//  R7 (this): allocation-minimal memory discipline. The L3 is 100% dirty
//    poison when our kernels run; every cache allocation forces a dirty-line
//    writeback to HBM. nt loads for read-once z (no 16MB allocate), nt stores
//    for zh (no dirty L2 at kernel boundary -> cheap interkernel flush).
//    Predict kernels ~31 -> ~23us, total ~68.

typedef float v4f __attribute__((ext_vector_type(4)));
typedef unsigned int v4u __attribute__((ext_vector_type(4)));
typedef unsigned int v2u __attribute__((ext_vector_type(2)));
typedef int v4i __attribute__((ext_vector_type(4)));

__device__ __forceinline__ float dot4v(v4f a, v4f b) {
  return a.x * b.x + a.y * b.y + a.z * b.z + a.w * b.w;
}

// 8-element fp16 dot with fp32 accumulate (4x half2 packed in v4u)
__device__ __forceinline__ float dot8h(v4u a, v4u b) {
  union { v4u u; __half2 h[4]; } au, bu;
  au.u = a; bu.u = b;
  float s = 0.0f;
#pragma unroll
  for (int k = 0; k < 4; ++k) {
    float2 af = __half22float2(au.h[k]);
    float2 bf = __half22float2(bu.h[k]);
    s += af.x * bf.x + af.y * bf.y;
  }
  return s;
}

// ---------------------------------------------------------------------------
// Kernel A: one wave per row. nt-reads fp32 z (16MB linear, read-once: no
// cache allocation -> no forced eviction of dirty poison), computes invnorm,
// nt-writes NORMALIZED fp16 row (8MB; bypasses L2 so the kernel-boundary
// flush has nothing to drain).
// ---------------------------------------------------------------------------
__global__ __launch_bounds__(256, 8) void norm_kernel(
    const float* __restrict__ zi, const float* __restrict__ zj,
    __half* __restrict__ zh) {
  const int wave = threadIdx.x >> 6;
  const int lane = threadIdx.x & 63;
  const int row  = blockIdx.x * 4 + wave;

  const v4f* a4 =
      (row < B_ROWS) ? (const v4f*)(zi + (size_t)row * D_DIM)
                     : (const v4f*)(zj + (size_t)(row - B_ROWS) * D_DIM);
  v4f a0 = __builtin_nontemporal_load(a4 + lane);
  v4f a1 = __builtin_nontemporal_load(a4 + lane + 64);
  float aa = dot4v(a0, a0) + dot4v(a1, a1);
#pragma unroll
  for (int off = 32; off > 0; off >>= 1) aa += __shfl_xor(aa, off);
  const float inv = 1.0f / fmaxf(sqrtf(aa), 1e-8f);

  // lane holds floats [4L..4L+3] and [256+4L..256+4L+3]; store as 2x 8B nt
  v2u* out = (v2u*)(zh + (size_t)row * D_DIM);
  union { v2u u; __half2 h[2]; } p0, p1;
  p0.h[0] = __floats2half2_rn(a0.x * inv, a0.y * inv);
  p0.h[1] = __floats2half2_rn(a0.z * inv, a0.w * inv);
  p1.h[0] = __floats2half2_rn(a1.x * inv, a1.y * inv);
  p1.h[1] = __floats2half2_rn(a1.z * inv, a1.w * inv);
  __builtin_nontemporal_store(p0.u, out + lane);
  __builtin_nontemporal_store(p1.u, out + lane + 64);
}

// ---------------------------------------------------------------------------
// Kernel B: gathered fp16 dots + log-softmax. One wave per row: 6 x 16B
// loads per lane, 5 fp32 accumulators, 5 wave reductions. Gathers stay
// cacheable (~6x grid-wide reuse per row). Dots of normalized rows ARE the
// cosine sims; logits = dot * INV_T. One plain store per block.
// ---------------------------------------------------------------------------
__global__ __launch_bounds__(256, 8) void loss_kernel(
    const __half* __restrict__ zh, const int* __restrict__ neg_idx,
    float* __restrict__ partials) {
  __shared__ float s_nll[4];

  const int wave = threadIdx.x >> 6;
  const int lane = threadIdx.x & 63;
  const int row  = blockIdx.x * 4 + wave;

  // Gathered column indices (wave-uniform values; nt read-once)
  const v4i nv = __builtin_nontemporal_load((const v4i*)neg_idx + row);
  int cols[5];
  cols[0] = (row + B_ROWS) & (N_ROWS - 1);       // positive column
  cols[1] = nv.x + (nv.x >= row ? 1 : 0);        // skip-diagonal mapping
  cols[2] = nv.y + (nv.y >= row ? 1 : 0);
  cols[3] = nv.z + (nv.z >= row ? 1 : 0);
  cols[4] = nv.w + (nv.w >= row ? 1 : 0);

  const v4u* a4 = (const v4u*)(zh + (size_t)row * D_DIM);
  v4u a = a4[lane];

  // Issue all 5 gather loads before any use (memory-level parallelism)
  v4u b[5];
#pragma unroll
  for (int c = 0; c < 5; ++c) {
    b[c] = ((const v4u*)(zh + (size_t)cols[c] * D_DIM))[lane];
  }

  float ab[5];
#pragma unroll
  for (int c = 0; c < 5; ++c) ab[c] = dot8h(a, b[c]);

  // 5 simultaneous wave reductions
#pragma unroll
  for (int o = 32; o > 0; o >>= 1) {
#pragma unroll
    for (int c = 0; c < 5; ++c) ab[c] += __shfl_down(ab[c], o);
  }

  if (lane == 0) {
    float logits[5];
    float m = -INFINITY;
#pragma unroll
    for (int c = 0; c < 5; ++c) {
      logits[c] = ab[c] * INV_T;
      m = fmaxf(m, logits[c]);
    }
    float sum = 0.0f;
#pragma unroll
    for (int c = 0; c < 5; ++c) sum += __expf(logits[c] - m);
    s_nll[wave] = -(logits[0] - m - __logf(sum));
  }
  __syncthreads();

  if (threadIdx.x == 0) {
    float r = s_nll[0] + s_nll[1] + s_nll[2] + s_nll[3];
    __builtin_nontemporal_store(r, partials + blockIdx.x);
  }
}

// ---------------------------------------------------------------------------
// Kernel C: reduce LOSS_BLOCKS partials -> mean -> out[0]. One block.
// ---------------------------------------------------------------------------
__global__ __launch_bounds__(256) void reduce_kernel(
    const float* __restrict__ partials, float* __restrict__ out) {
  __shared__ float smem[4];
  const int lane = threadIdx.x & 63;
  const int wave = threadIdx.x >> 6;
  float s = 0.0f;
#pragma unroll
  for (int i = 0; i < RED_ITERS; ++i) s += partials[i * 256 + threadIdx.x];
#pragma unroll
  for (int off = 32; off > 0; off >>= 1) s += __shfl_down(s, off);
  if (lane == 0) smem[wave] = s;
  __syncthreads();
  if (threadIdx.x == 0) {
    out[0] = (smem[0] + smem[1] + smem[2] + smem[3]) * (1.0f / (float)N_ROWS);
  }
}

extern "C" void kernel_launch(void* const* d_in, const int* in_sizes, int n_in,
                              void* d_out, int out_size, void* d_ws,
                              size_t ws_size, hipStream_t stream) {
  const float* zi      = (const float*)d_in[0];
  const float* zj      = (const float*)d_in[1];
  const int*   neg_idx = (const int*)d_in[2];
  float* out = (float*)d_out;

  char* w = (char*)d_ws;
  __half* zh       = (__half*)w;                                 // 8 MB
  float*  partials = (float*)(w + (size_t)N_ROWS * D_DIM * sizeof(__half));

  norm_kernel<<<dim3(NORM_BLOCKS), dim3(256), 0, stream>>>(zi, zj, zh);
  loss_kernel<<<dim3(LOSS_BLOCKS), dim3(256), 0, stream>>>(zh, neg_idx,
                                                           partials);
  reduce_kernel<<<dim3(1), dim3(256), 0, stream>>>(partials, out);
}

// Round 6
// 77.738 us; speedup vs baseline: 1.0536x; 1.0536x over previous
//
#include <hip/hip_runtime.h>
#include <hip/hip_fp16.h>
#include <math.h>

// Problem constants (match reference)
#define B_ROWS 4096
#define D_DIM  512
#define N_ROWS 8192
#define R_NEG  4

// 1/(TEMPERATURE + EPSILON): fp32(1/(0.5+1e-8)) == 2.0f (verified absmax 0.0 in R1)
#define INV_T 2.0f

#define NORM_BLOCKS (N_ROWS / 4)  // kernel A: 4 waves/block, 1 row/wave
#define PAIR_BLOCKS (B_ROWS / 4)  // kernel B: 4 waves/block, 1 ROW-PAIR/wave
#define RED_ITERS   (PAIR_BLOCKS / 256)

// Journal (kernel portion = dur_us - fill; fill has +-5us session noise):
//  R0-R4 (prev session): 268MB poison fill @~6TB/s = 42-47us fixed floor.
//    No atomics (R3: 2048 same-addr ~30cyc each). No fence (R2: +81us).
//  R5: 2x waves on loss -> NULL. Not occupancy-bound.  [portion 37->42]
//  R6: fp16 normalized zh, 3-kernel split -> portion 37.2 -> 30.9. Weakly
//    byte-bound: halved gather bytes bought only ~6us.
//  R7: nt loads/stores -> portion 34.9 (WORSE +4). Fill's WRITE_SIZE=268MB
//    proves poison fully drains during fill; caches clean-but-cold at our
//    start. nt stores evicted zh from L2 -> loss kernel lost reuse. REVERTED.
//  R8: row-pairing — STILL UNTESTED: R4 and R5 benches both died with
//    "MI355X container failed twice" (broker-level infra failure, no compile
//    or correctness signal; source audited in-bounds, no hang vectors).
//    Resubmitting unchanged. positives[i]=sim[i,i+B]=positives[i+B]: one
//    wave handles rows (i, i+B): 10 gathers + 9 dots for 2 rows (was
//    12+10), all 10 loads in flight before first use (1.67x MLP). lb(256,6).

typedef float v4f __attribute__((ext_vector_type(4)));
typedef unsigned int v4u __attribute__((ext_vector_type(4)));
typedef unsigned int v2u __attribute__((ext_vector_type(2)));

__device__ __forceinline__ float dot4v(v4f a, v4f b) {
  return a.x * b.x + a.y * b.y + a.z * b.z + a.w * b.w;
}

// 8-element fp16 dot with fp32 accumulate (4x half2 packed in v4u)
__device__ __forceinline__ float dot8h(v4u a, v4u b) {
  union { v4u u; __half2 h[4]; } au, bu;
  au.u = a; bu.u = b;
  float s = 0.0f;
#pragma unroll
  for (int k = 0; k < 4; ++k) {
    float2 af = __half22float2(au.h[k]);
    float2 bf = __half22float2(bu.h[k]);
    s += af.x * bf.x + af.y * bf.y;
  }
  return s;
}

// ---------------------------------------------------------------------------
// Kernel A: one wave per row. Reads fp32 z (16MB linear), writes NORMALIZED
// fp16 row (8MB) through the cache (loss kernel reuses from L2/L3 — R7
// showed nt stores here cost +4us).
// ---------------------------------------------------------------------------
__global__ __launch_bounds__(256, 8) void norm_kernel(
    const float* __restrict__ zi, const float* __restrict__ zj,
    __half* __restrict__ zh) {
  const int wave = threadIdx.x >> 6;
  const int lane = threadIdx.x & 63;
  const int row  = blockIdx.x * 4 + wave;

  const v4f* a4 =
      (row < B_ROWS) ? (const v4f*)(zi + (size_t)row * D_DIM)
                     : (const v4f*)(zj + (size_t)(row - B_ROWS) * D_DIM);
  v4f a0 = a4[lane];
  v4f a1 = a4[lane + 64];
  float aa = dot4v(a0, a0) + dot4v(a1, a1);
#pragma unroll
  for (int off = 32; off > 0; off >>= 1) aa += __shfl_xor(aa, off);
  const float inv = 1.0f / fmaxf(sqrtf(aa), 1e-8f);

  v2u* out = (v2u*)(zh + (size_t)row * D_DIM);
  union { v2u u; __half2 h[2]; } p0, p1;
  p0.h[0] = __floats2half2_rn(a0.x * inv, a0.y * inv);
  p0.h[1] = __floats2half2_rn(a0.z * inv, a0.w * inv);
  p1.h[0] = __floats2half2_rn(a1.x * inv, a1.y * inv);
  p1.h[1] = __floats2half2_rn(a1.z * inv, a1.w * inv);
  out[lane]      = p0.u;
  out[lane + 64] = p1.u;
}

// ---------------------------------------------------------------------------
// Kernel B: one wave per ROW-PAIR (i, i+B). The positive dot a_i . a_{i+B}
// is shared by both rows' softmax. 10 gather loads (a_i, a_{i+B}, 4+4 negs)
// all issued before first use; 9 simultaneous wave reductions. lane 0 does
// two 5-way log-softmaxes. One plain store per block.
// ---------------------------------------------------------------------------
__global__ __launch_bounds__(256, 6) void loss_kernel(
    const __half* __restrict__ zh, const int* __restrict__ neg_idx,
    float* __restrict__ partials) {
  __shared__ float s_nll[4];

  const int wave = threadIdx.x >> 6;
  const int lane = threadIdx.x & 63;
  const int row0 = blockIdx.x * 4 + wave;   // in [0, B)
  const int row1 = row0 + B_ROWS;           // its positive partner

  // Gathered column indices for both rows (wave-uniform)
  const int4 nv0 = ((const int4*)neg_idx)[row0];
  const int4 nv1 = ((const int4*)neg_idx)[row1];
  int c0[4], c1[4];
  c0[0] = nv0.x + (nv0.x >= row0 ? 1 : 0);
  c0[1] = nv0.y + (nv0.y >= row0 ? 1 : 0);
  c0[2] = nv0.z + (nv0.z >= row0 ? 1 : 0);
  c0[3] = nv0.w + (nv0.w >= row0 ? 1 : 0);
  c1[0] = nv1.x + (nv1.x >= row1 ? 1 : 0);
  c1[1] = nv1.y + (nv1.y >= row1 ? 1 : 0);
  c1[2] = nv1.z + (nv1.z >= row1 ? 1 : 0);
  c1[3] = nv1.w + (nv1.w >= row1 ? 1 : 0);

  // Issue ALL 10 gather loads before any use (max memory-level parallelism)
  const v4u* base = (const v4u*)zh;
  v4u a0 = base[(size_t)row0 * 64 + lane];
  v4u a1 = base[(size_t)row1 * 64 + lane];
  v4u b0[4], b1[4];
#pragma unroll
  for (int c = 0; c < 4; ++c) b0[c] = base[(size_t)c0[c] * 64 + lane];
#pragma unroll
  for (int c = 0; c < 4; ++c) b1[c] = base[(size_t)c1[c] * 64 + lane];

  // 9 per-lane partial dots: shared positive + 4 negs per row
  float pos = dot8h(a0, a1);
  float n0[4], n1[4];
#pragma unroll
  for (int c = 0; c < 4; ++c) n0[c] = dot8h(a0, b0[c]);
#pragma unroll
  for (int c = 0; c < 4; ++c) n1[c] = dot8h(a1, b1[c]);

  // 9 simultaneous wave reductions
#pragma unroll
  for (int o = 32; o > 0; o >>= 1) {
    pos += __shfl_down(pos, o);
#pragma unroll
    for (int c = 0; c < 4; ++c) {
      n0[c] += __shfl_down(n0[c], o);
      n1[c] += __shfl_down(n1[c], o);
    }
  }

  if (lane == 0) {
    const float lp = pos * INV_T;
    // row0 softmax
    float m0 = lp, s0;
    float l0[4], l1[4];
#pragma unroll
    for (int c = 0; c < 4; ++c) { l0[c] = n0[c] * INV_T; m0 = fmaxf(m0, l0[c]); }
    s0 = __expf(lp - m0);
#pragma unroll
    for (int c = 0; c < 4; ++c) s0 += __expf(l0[c] - m0);
    const float nll0 = -(lp - m0 - __logf(s0));
    // row1 softmax
    float m1 = lp, s1;
#pragma unroll
    for (int c = 0; c < 4; ++c) { l1[c] = n1[c] * INV_T; m1 = fmaxf(m1, l1[c]); }
    s1 = __expf(lp - m1);
#pragma unroll
    for (int c = 0; c < 4; ++c) s1 += __expf(l1[c] - m1);
    const float nll1 = -(lp - m1 - __logf(s1));
    s_nll[wave] = nll0 + nll1;
  }
  __syncthreads();

  if (threadIdx.x == 0) {
    partials[blockIdx.x] = s_nll[0] + s_nll[1] + s_nll[2] + s_nll[3];
  }
}

// ---------------------------------------------------------------------------
// Kernel C: reduce PAIR_BLOCKS partials -> mean -> out[0]. One block.
// ---------------------------------------------------------------------------
__global__ __launch_bounds__(256) void reduce_kernel(
    const float* __restrict__ partials, float* __restrict__ out) {
  __shared__ float smem[4];
  const int lane = threadIdx.x & 63;
  const int wave = threadIdx.x >> 6;
  float s = 0.0f;
#pragma unroll
  for (int i = 0; i < RED_ITERS; ++i) s += partials[i * 256 + threadIdx.x];
#pragma unroll
  for (int off = 32; off > 0; off >>= 1) s += __shfl_down(s, off);
  if (lane == 0) smem[wave] = s;
  __syncthreads();
  if (threadIdx.x == 0) {
    out[0] = (smem[0] + smem[1] + smem[2] + smem[3]) * (1.0f / (float)N_ROWS);
  }
}

extern "C" void kernel_launch(void* const* d_in, const int* in_sizes, int n_in,
                              void* d_out, int out_size, void* d_ws,
                              size_t ws_size, hipStream_t stream) {
  const float* zi      = (const float*)d_in[0];
  const float* zj      = (const float*)d_in[1];
  const int*   neg_idx = (const int*)d_in[2];
  float* out = (float*)d_out;

  char* w = (char*)d_ws;
  __half* zh       = (__half*)w;                                 // 8 MB
  float*  partials = (float*)(w + (size_t)N_ROWS * D_DIM * sizeof(__half));

  norm_kernel<<<dim3(NORM_BLOCKS), dim3(256), 0, stream>>>(zi, zj, zh);
  loss_kernel<<<dim3(PAIR_BLOCKS), dim3(256), 0, stream>>>(zh, neg_idx,
                                                           partials);
  reduce_kernel<<<dim3(1), dim3(256), 0, stream>>>(partials, out);
}